// Round 5
// baseline (59.779 us; speedup 1.0000x reference)
//
#include <hip/hip_runtime.h>
#include <stdint.h>

// Spatial transformer: batched dense-displacement trilinear warp, LDS-staged.
// vol: [B=2, D=128, H=192, W=192, 1] f32
// trf: [B=2, D=128, H=192, W=192, 3] f32 (displacement along z,y,x)
// out: [B=2, D=128, H=192, W=192, 1] f32

#define BD 128
#define BH 192
#define BW 192
#define DHW (BD*BH*BW)
#define NB 2

// output tile per block: 64 x * 8 y * 4 z = 2048 voxels, 256 thr * 8 vox
#define TX 64
#define TY 8
#define TZ 4
#define NTX (BW/TX)                 // 3
#define NTY (BH/TY)                 // 24
#define NTZ (BD/TZ)                 // 32
#define NBLK (NTX*NTY*NTZ*NB)       // 4608  (% 8 == 0)
#define NXCD 8

// staged window (floats): x 72 [tx-4..tx+67], y 15 [ty-3..ty+11], z 12 [tz-4..tz+7]
// membership is TESTED exactly per sample; misses take the global fallback.
#define SXW 72
#define SYW 15
#define SZW 12
#define SROWS (SYW*SZW)             // 180 rows
#define SF4ROW (SXW/4)              // 18 float4 per row
#define SF4 (SROWS*SF4ROW)          // 3240 float4 staged
#define LDSF (SXW*SROWS)            // 12960 floats = 51840 B -> 3 blocks/CU

typedef float f4v __attribute__((ext_vector_type(4)));

__global__ __launch_bounds__(256) void st_warp_kernel(
    const float* __restrict__ vol,
    const float* __restrict__ trf,
    float* __restrict__ out)
{
    __shared__ __align__(16) float lds[LDSF + 4];   // +pad (x0==191 reads lds[i+1])

    // XCD-chunked swizzle: each XCD gets a contiguous chunk of 576 blocks
    const int bid = blockIdx.x;
    const int swz = (bid % NXCD) * (NBLK / NXCD) + bid / NXCD;
    int tmp = swz;
    const int txi = tmp % NTX; tmp /= NTX;
    const int tyi = tmp % NTY; tmp /= NTY;
    const int tzi = tmp % NTZ; tmp /= NTZ;
    const int b   = tmp;
    const int tx = txi*TX, ty = tyi*TY, tz = tzi*TZ;

    // staged window origin (sx stays 4-aligned: tx-4 in {-4,60,124} -> {0,60,120})
    const int sx = min(max(tx - 4, 0), BW - SXW);
    const int sy = min(max(ty - 3, 0), BH - SYW);
    const int sz = min(max(tz - 4, 0), BD - SZW);

    const int tid = (int)threadIdx.x;
    const float* volb = vol + (size_t)b * DHW;

    // ---------- phase 1: ISSUE vol staging first (vmcnt-tracked, no deps) ----------
#pragma unroll
    for (int it = 0; it < 13; ++it) {
        const int f = tid + it*256;
        if (f < SF4) {
            const int r  = f / SF4ROW;          // staged row
            const int c  = f - r*SF4ROW;
            const int zi = r / SYW;
            const int yi = r - zi*SYW;
            const float* g = volb + ((size_t)((sz+zi)*BH + (sy+yi)))*BW + sx + c*4;
            __builtin_amdgcn_global_load_lds(
                (const __attribute__((address_space(1))) void*)g,
                (__attribute__((address_space(3))) void*)&lds[f*4],
                16, 0, 0);
        }
    }
    if (tid == 0) lds[LDSF] = 0.0f;             // finite pad for the x==191 corner

    // ---------- phase 2: trf direct loads -> regs (overlaps staging latency) ----
    // thread's voxel-quad (i=0,1): gi=i*256+tid -> same mapping as compute phase.
    // 12 contiguous floats per quad = 3 float4 (48B-aligned).
    const f4v* trf4 = (const f4v*)trf;
    f4v tA[2], tB[2], tC[2];
#pragma unroll
    for (int i = 0; i < 2; ++i) {
        const int gi = i*256 + tid;
        const int xg = gi & 15;
        const int yb = (gi >> 4) & 7;
        const int zb = gi >> 7;
        const size_t rowb = ((size_t)((b*BD + tz+zb)*BH + ty+yb)*BW + tx) * 3 / 4;
        tA[i] = __builtin_nontemporal_load(&trf4[rowb + 3*xg + 0]);
        tB[i] = __builtin_nontemporal_load(&trf4[rowb + 3*xg + 1]);
        tC[i] = __builtin_nontemporal_load(&trf4[rowb + 3*xg + 2]);
    }

    __syncthreads();                            // drains vmcnt (staging) + lgkm

    // ---------- phase 3: sample 8 voxels from LDS (rare global fallback) ----------
#pragma unroll
    for (int i = 0; i < 2; ++i) {
        const float dzs[4] = {tA[i].x, tA[i].w, tB[i].z, tC[i].y};
        const float dys[4] = {tA[i].y, tB[i].x, tB[i].w, tC[i].z};
        const float dxs[4] = {tA[i].z, tB[i].y, tC[i].x, tC[i].w};
        const int gi = i*256 + tid;
        const int xg = gi & 15;
        const int yb = (gi >> 4) & 7;
        const int zb = gi >> 7;
        const int Y  = ty + yb;
        const int Z  = tz + zb;
        const int Xb = tx + xg*4;
        float res[4];
#pragma unroll
        for (int jj = 0; jj < 4; ++jj) {
            float cz = fminf(fmaxf((float)Z + dzs[jj], 0.f), (float)(BD-1));
            float cy = fminf(fmaxf((float)Y + dys[jj], 0.f), (float)(BH-1));
            float cx = fminf(fmaxf((float)(Xb+jj) + dxs[jj], 0.f), (float)(BW-1));
            float fz = floorf(cz), fy = floorf(cy), fx = floorf(cx);
            int z0 = (int)fz, y0 = (int)fy, x0 = (int)fx;
            int z1 = min(z0+1, BD-1);
            int y1 = min(y0+1, BH-1);
            int x1 = min(x0+1, BW-1);
            float wz = cz - fz, wy = cy - fy, wx = cx - fx;
            float v000,v001,v010,v011,v100,v101,v110,v111;
            bool inwin = (x0 >= sx) & (x1 <= sx+SXW-1) & (y0 >= sy) & (y1 <= sy+SYW-1)
                       & (z0 >= sz) & (z1 <= sz+SZW-1);
            if (inwin) {
                const int zi0 = z0 - sz, zi1 = z1 - sz;
                const int yi0 = y0 - sy, yi1 = y1 - sy;
                const int xi  = x0 - sx;
                const int i00 = (zi0*SYW + yi0)*SXW + xi;
                const int i01 = (zi0*SYW + yi1)*SXW + xi;
                const int i10 = (zi1*SYW + yi0)*SXW + xi;
                const int i11 = (zi1*SYW + yi1)*SXW + xi;
                // x0==x1 (==191) reads a stray lds word at +1, but wx==0 and it is finite
                v000 = lds[i00]; v001 = lds[i00+1];
                v010 = lds[i01]; v011 = lds[i01+1];
                v100 = lds[i10]; v101 = lds[i10+1];
                v110 = lds[i11]; v111 = lds[i11+1];
            } else {
                const float* p00 = volb + ((size_t)z0*BH + y0)*BW;
                const float* p01 = volb + ((size_t)z0*BH + y1)*BW;
                const float* p10 = volb + ((size_t)z1*BH + y0)*BW;
                const float* p11 = volb + ((size_t)z1*BH + y1)*BW;
                v000 = p00[x0]; v001 = p00[x1];
                v010 = p01[x0]; v011 = p01[x1];
                v100 = p10[x0]; v101 = p10[x1];
                v110 = p11[x0]; v111 = p11[x1];
            }
            float c00 = v000 + wx*(v001-v000);
            float c01 = v010 + wx*(v011-v010);
            float c10 = v100 + wx*(v101-v100);
            float c11 = v110 + wx*(v111-v110);
            float c0  = c00 + wy*(c01-c00);
            float c1  = c10 + wy*(c11-c10);
            res[jj]   = c0 + wz*(c1-c0);
        }
        f4v r = {res[0], res[1], res[2], res[3]};
        const size_t of4 = ((size_t)((b*BD + Z)*BH + Y)*BW + Xb) / 4;
        __builtin_nontemporal_store(r, &((f4v*)out)[of4]);
    }
}

extern "C" void kernel_launch(void* const* d_in, const int* in_sizes, int n_in,
                              void* d_out, int out_size, void* d_ws, size_t ws_size,
                              hipStream_t stream) {
    const float* vol = (const float*)d_in[0];
    const float* trf = (const float*)d_in[1];
    float* out = (float*)d_out;

    st_warp_kernel<<<dim3(NBLK), dim3(256), 0, stream>>>(vol, trf, out);
}

// Round 6
// 51.476 us; speedup vs baseline: 1.1613x; 1.1613x over previous
//
#include <hip/hip_runtime.h>
#include <stdint.h>

// Spatial transformer: batched dense-displacement trilinear warp, LDS-staged.
// vol: [B=2, D=128, H=192, W=192, 1] f32
// trf: [B=2, D=128, H=192, W=192, 3] f32 (displacement along z,y,x)
// out: [B=2, D=128, H=192, W=192, 1] f32

#define BD 128
#define BH 192
#define BW 192
#define DHW (BD*BH*BW)
#define NB 2

// output tile per block: 16 x * 16 y * 8 z = 2048 voxels, 256 thr * 8 vox
#define TX 16
#define TY 16
#define TZ 8
#define NTX (BW/TX)                 // 12
#define NTY (BH/TY)                 // 12
#define NTZ (BD/TZ)                 // 16
#define NBLK (NTX*NTY*NTZ*NB)       // 4608  (% 8 == 0)
#define NXCD 8

// staged window (floats): x 25 [tx-4..tx+20], y 24 [ty-4..ty+19], z 16 [tz-4..tz+11]
// full +-4 halos in all dims -> fallback P ~ 1.9e-4/voxel.
// SXW=25 (odd) -> LDS row stride spans all 32 banks -> conflict-free corner reads.
#define SXW 25
#define SYW 24
#define SZW 16
#define SLAB (SXW*SYW)              // 600 floats per z-slab
#define LDSF (SLAB*SZW)             // 9600 floats = 38400 B -> 4 blocks/CU

typedef float f4v __attribute__((ext_vector_type(4)));

__global__ __launch_bounds__(256, 4) void st_warp_kernel(
    const float* __restrict__ vol,
    const float* __restrict__ trf,
    float* __restrict__ out)
{
    __shared__ float lds[LDSF + 4];   // +4 pad for the x0==191 stray read

    // XCD-chunked swizzle: each XCD gets a contiguous chunk of 576 blocks
    const int bid = blockIdx.x;
    const int swz = (bid % NXCD) * (NBLK / NXCD) + bid / NXCD;
    int tmp = swz;
    const int txi = tmp % NTX; tmp /= NTX;
    const int tyi = tmp % NTY; tmp /= NTY;
    const int tzi = tmp % NTZ; tmp /= NTZ;
    const int b   = tmp;
    const int tx = txi*TX, ty = tyi*TY, tz = tzi*TZ;

    const int sx = min(max(tx - 4, 0), BW - SXW);
    const int sy = min(max(ty - 4, 0), BH - SYW);
    const int sz = min(max(tz - 4, 0), BD - SZW);

    const int tid = (int)threadIdx.x;
    const float* volb = vol + (size_t)b * DHW;

    // ---------- phase 1: ISSUE vol staging (width-4, per-lane global addr) -------
    // LDS stays lane-linear (required); rows are 25 floats = 100B, so each lane
    // computes its own (zi,yi,xi) from the linear float index p.
#pragma unroll
    for (int it = 0; it < 38; ++it) {
        const int p = tid + it*256;
        if (p < LDSF) {
            const int zi  = p / SLAB;
            const int rem = p - zi*SLAB;
            const int yi  = rem / SXW;
            const int xi  = rem - yi*SXW;
            const float* g = volb + ((size_t)((sz+zi)*BH + (sy+yi)))*BW + sx + xi;
            __builtin_amdgcn_global_load_lds(
                (const __attribute__((address_space(1))) void*)g,
                (__attribute__((address_space(3))) void*)&lds[p],
                4, 0, 0);
        }
    }
    if (tid < 4) lds[LDSF + tid] = 0.0f;        // finite pad (avoid 0*NaN)

    // ---------- phase 2: trf direct loads -> regs (overlap staging latency) -----
    // quad gi = i*256+tid: xq=gi&3, yb=(gi>>2)&15, zb=gi>>6 (zb uniform per wave).
    const f4v* trf4 = (const f4v*)trf;
    f4v tA[2], tB[2], tC[2];
#pragma unroll
    for (int i = 0; i < 2; ++i) {
        const int gi = i*256 + tid;
        const int xq = gi & 3;
        const int yb = (gi >> 2) & 15;
        const int zb = gi >> 6;
        const size_t rowf4 = ((size_t)((b*BD + tz+zb)*BH + ty+yb)*BW + tx) * 3 / 4;
        tA[i] = trf4[rowf4 + 3*xq + 0];
        tB[i] = trf4[rowf4 + 3*xq + 1];
        tC[i] = trf4[rowf4 + 3*xq + 2];
    }

    __syncthreads();                            // drains vmcnt (staging) + lgkm

    // ---------- phase 3: sample 8 voxels from LDS (rare global fallback) --------
#pragma unroll
    for (int i = 0; i < 2; ++i) {
        const float dzs[4] = {tA[i].x, tA[i].w, tB[i].z, tC[i].y};
        const float dys[4] = {tA[i].y, tB[i].x, tB[i].w, tC[i].z};
        const float dxs[4] = {tA[i].z, tB[i].y, tC[i].x, tC[i].w};
        const int gi = i*256 + tid;
        const int xq = gi & 3;
        const int yb = (gi >> 2) & 15;
        const int zb = gi >> 6;
        const int Y  = ty + yb;
        const int Z  = tz + zb;
        const int Xb = tx + xq*4;
        float res[4];
#pragma unroll
        for (int jj = 0; jj < 4; ++jj) {
            float cz = fminf(fmaxf((float)Z + dzs[jj], 0.f), (float)(BD-1));
            float cy = fminf(fmaxf((float)Y + dys[jj], 0.f), (float)(BH-1));
            float cx = fminf(fmaxf((float)(Xb+jj) + dxs[jj], 0.f), (float)(BW-1));
            float fz = floorf(cz), fy = floorf(cy), fx = floorf(cx);
            int z0 = (int)fz, y0 = (int)fy, x0 = (int)fx;
            int z1 = min(z0+1, BD-1);
            int y1 = min(y0+1, BH-1);
            int x1 = min(x0+1, BW-1);
            float wz = cz - fz, wy = cy - fy, wx = cx - fx;
            float v000,v001,v010,v011,v100,v101,v110,v111;
            bool inwin = (x0 >= sx) & (x1 <= sx+SXW-1) & (y0 >= sy) & (y1 <= sy+SYW-1)
                       & (z0 >= sz) & (z1 <= sz+SZW-1);
            if (inwin) {
                const int zi0 = z0 - sz, zi1 = z1 - sz;
                const int yi0 = y0 - sy, yi1 = y1 - sy;
                const int xi  = x0 - sx;
                const int i00 = zi0*SLAB + yi0*SXW + xi;
                const int i01 = zi0*SLAB + yi1*SXW + xi;
                const int i10 = zi1*SLAB + yi0*SXW + xi;
                const int i11 = zi1*SLAB + yi1*SXW + xi;
                // x0==x1(==191) reads a stray word at +1: finite, weighted by wx==0
                v000 = lds[i00]; v001 = lds[i00+1];
                v010 = lds[i01]; v011 = lds[i01+1];
                v100 = lds[i10]; v101 = lds[i10+1];
                v110 = lds[i11]; v111 = lds[i11+1];
            } else {
                const float* p00 = volb + ((size_t)z0*BH + y0)*BW;
                const float* p01 = volb + ((size_t)z0*BH + y1)*BW;
                const float* p10 = volb + ((size_t)z1*BH + y0)*BW;
                const float* p11 = volb + ((size_t)z1*BH + y1)*BW;
                v000 = p00[x0]; v001 = p00[x1];
                v010 = p01[x0]; v011 = p01[x1];
                v100 = p10[x0]; v101 = p10[x1];
                v110 = p11[x0]; v111 = p11[x1];
            }
            float c00 = v000 + wx*(v001-v000);
            float c01 = v010 + wx*(v011-v010);
            float c10 = v100 + wx*(v101-v100);
            float c11 = v110 + wx*(v111-v110);
            float c0  = c00 + wy*(c01-c00);
            float c1  = c10 + wy*(c11-c10);
            res[jj]   = c0 + wz*(c1-c0);
        }
        f4v r = {res[0], res[1], res[2], res[3]};
        const size_t of4 = ((size_t)((b*BD + Z)*BH + Y)*BW + Xb) / 4;
        __builtin_nontemporal_store(r, &((f4v*)out)[of4]);
    }
}

extern "C" void kernel_launch(void* const* d_in, const int* in_sizes, int n_in,
                              void* d_out, int out_size, void* d_ws, size_t ws_size,
                              hipStream_t stream) {
    const float* vol = (const float*)d_in[0];
    const float* trf = (const float*)d_in[1];
    float* out = (float*)d_out;

    st_warp_kernel<<<dim3(NBLK), dim3(256), 0, stream>>>(vol, trf, out);
}